// Round 7
// baseline (196.108 us; speedup 1.0000x reference)
//
#include <hip/hip_runtime.h>

#define D_MODEL 1024
#define NUM_HEADS 16
#define DH 64
#define B_SZ 2
#define T_SZ 2048
#define M_ROWS (B_SZ * T_SZ)   // 4096

typedef __bf16 bf16;
typedef __bf16 bf16x4 __attribute__((ext_vector_type(4)));
typedef __bf16 bf16x8 __attribute__((ext_vector_type(8)));
typedef float f32x4 __attribute__((ext_vector_type(4)));

__device__ __forceinline__ void async_copy16(const bf16* g, bf16* l) {
  __builtin_amdgcn_global_load_lds(
      (const __attribute__((address_space(1))) void*)g,
      (__attribute__((address_space(3))) void*)l, 16, 0, 0);
}

// ---------------------------------------------------------------------------
// 1. Cast fp32 -> bf16
// ---------------------------------------------------------------------------
#define NX (M_ROWS * D_MODEL / 4)
#define NW (D_MODEL * D_MODEL / 4)

__global__ __launch_bounds__(256) void cast_all(
    const float* __restrict__ X, const float* __restrict__ Wq,
    const float* __restrict__ Wk, const float* __restrict__ Wv,
    const float* __restrict__ Wo,
    bf16* __restrict__ Xb, bf16* __restrict__ Wqb, bf16* __restrict__ Wkb,
    bf16* __restrict__ Wvb, bf16* __restrict__ Wob) {
  int i = blockIdx.x * 256 + threadIdx.x;
  const float* s; bf16* d; int off;
  if (i < NX) {
    s = X; d = Xb; off = i;
  } else {
    int j = i - NX;
    int w = j >> 18;
    off = j & (NW - 1);
    if (w == 0)      { s = Wq; d = Wqb; }
    else if (w == 1) { s = Wk; d = Wkb; }
    else if (w == 2) { s = Wv; d = Wvb; }
    else             { s = Wo; d = Wob; }
  }
  float4 v = ((const float4*)s)[off];
  bf16x4 o;
  o[0] = (bf16)v.x; o[1] = (bf16)v.y; o[2] = (bf16)v.z; o[3] = (bf16)v.w;
  ((bf16x4*)d)[off] = o;
}

// ---------------------------------------------------------------------------
// 2. QKV GEMM, m97 structure (unchanged)
// ---------------------------------------------------------------------------
__global__ __launch_bounds__(256) void qkv_gemm(
    const bf16* __restrict__ Xb,
    const bf16* __restrict__ Wqb, const bf16* __restrict__ Wkb,
    const bf16* __restrict__ Wvb,
    bf16* __restrict__ Q, bf16* __restrict__ K, bf16* __restrict__ V) {
  __shared__ bf16 As[128 * 32];
  __shared__ bf16 Bs[128 * 32];

  int tid = threadIdx.x;
  int wave = tid >> 6, lane = tid & 63;
  int wm = wave >> 1, wn = wave & 1;
  int l15 = lane & 15, quad = lane >> 4;

  int row0 = blockIdx.x * 128;
  int col0 = blockIdx.y * 128;
  int sel = col0 >> 10;
  int nb = col0 & 1023;
  const bf16* W; bf16* Out;
  if (sel == 0)      { W = Wqb; Out = Q; }
  else if (sel == 1) { W = Wkb; Out = K; }
  else               { W = Wvb; Out = V; }

  int srow = tid >> 2;
  int schunk = tid & 3;
  const bf16* Ag = Xb + (size_t)(row0 + srow) * D_MODEL + schunk * 8;
  const bf16* Bg = W + (size_t)(nb + srow) * D_MODEL + schunk * 8;
  bf16* Al0 = &As[srow * 32 + schunk * 8];
  bf16* Al1 = &As[(srow + 64) * 32 + schunk * 8];
  bf16* Bl0 = &Bs[srow * 32 + schunk * 8];
  bf16* Bl1 = &Bs[(srow + 64) * 32 + schunk * 8];

  f32x4 acc[4][4];
#pragma unroll
  for (int i = 0; i < 4; ++i)
#pragma unroll
    for (int j = 0; j < 4; ++j) acc[i][j] = (f32x4){0.f, 0.f, 0.f, 0.f};

  for (int k0 = 0; k0 < D_MODEL; k0 += 32) {
    async_copy16(Ag + k0, Al0);
    async_copy16(Ag + k0 + (size_t)64 * D_MODEL, Al1);
    async_copy16(Bg + k0, Bl0);
    async_copy16(Bg + k0 + (size_t)64 * D_MODEL, Bl1);
    __syncthreads();

    bf16x8 af[4], bfr[4];
#pragma unroll
    for (int i = 0; i < 4; ++i)
      af[i] = *(const bf16x8*)&As[(wm * 64 + i * 16 + l15) * 32 + quad * 8];
#pragma unroll
    for (int j = 0; j < 4; ++j)
      bfr[j] = *(const bf16x8*)&Bs[(wn * 64 + j * 16 + l15) * 32 + quad * 8];
#pragma unroll
    for (int i = 0; i < 4; ++i)
#pragma unroll
      for (int j = 0; j < 4; ++j)
        acc[i][j] = __builtin_amdgcn_mfma_f32_16x16x32_bf16(af[i], bfr[j],
                                                            acc[i][j], 0, 0, 0);
    __syncthreads();
  }

#pragma unroll
  for (int i = 0; i < 4; ++i) {
    int row = row0 + wm * 64 + i * 16 + quad * 4;
#pragma unroll
    for (int j = 0; j < 4; ++j) {
      int col = nb + wn * 64 + j * 16 + l15;
#pragma unroll
      for (int r = 0; r < 4; ++r)
        Out[(size_t)(row + r) * D_MODEL + col] = (bf16)acc[i][j][r];
    }
  }
}

// ---------------------------------------------------------------------------
// 3. Fused: RoPE on K (in place) + V transpose. One launch, two block ranges.
// ---------------------------------------------------------------------------
#define ROPEK_BLOCKS (M_ROWS * NUM_HEADS * 32 / 256)   // 8192

__global__ __launch_bounds__(256) void ropek_vt(
    bf16* __restrict__ K, const bf16* __restrict__ V, bf16* __restrict__ VT,
    const int* __restrict__ pos) {
  int b0 = blockIdx.x;
  if (b0 < ROPEK_BLOCKS) {
    int idx = b0 * 256 + threadIdx.x;
    int i = idx & 31;
    int h = (idx >> 5) & 15;
    int row = idx >> 9;
    int t = row & (T_SZ - 1);
    float p = (float)pos[t];
    float freq = __expf(-(float)i * 0.28782313662425f);  // ln(1e4)/32
    float s, c;
    sincosf(p * freq, &s, &c);
    size_t base = (size_t)row * D_MODEL + h * DH + 2 * i;
    float k1 = (float)K[base], k2 = (float)K[base + 1];
    K[base]     = (bf16)(k1 * c - k2 * s);
    K[base + 1] = (bf16)(k1 * s + k2 * c);
  } else {
    __shared__ bf16 tile[64][72];
    int vb = b0 - ROPEK_BLOCKS;     // 0..1023
    int bh = vb >> 5;               // 32
    int tt = vb & 31;               // 32
    int b = bh >> 4, h = bh & 15;
    int tid = threadIdx.x;
    int rr = tid >> 3;
    int cc = (tid & 7) * 8;
#pragma unroll
    for (int p = 0; p < 2; ++p) {
      int t = rr + p * 32;
      bf16x8 v = *(const bf16x8*)&V[((size_t)b * T_SZ + tt * 64 + t) * D_MODEL +
                                    h * DH + cc];
      *(bf16x8*)&tile[t][cc] = v;
    }
    __syncthreads();
#pragma unroll
    for (int p = 0; p < 2; ++p) {
      int d = rr + p * 32;
      bf16x8 o;
#pragma unroll
      for (int j = 0; j < 8; ++j) o[j] = tile[cc + j][d];
      *(bf16x8*)&VT[((size_t)bh * DH + d) * T_SZ + tt * 64 + cc] = o;
    }
  }
}

// ---------------------------------------------------------------------------
// 4. Causal flash attention: 8 waves / block, q-tile 128 (wave owns 16 rows),
//    kv chunks of 64 staged to LDS (waves 0-3: K halves, waves 4-7: VT halves).
//    S^T formulation, no-running-max unnormalized softmax, Q-RoPE in-register.
// ---------------------------------------------------------------------------
#define PST 72

__global__ __launch_bounds__(512) void attn_kernel(
    const bf16* __restrict__ Q, const bf16* __restrict__ K,
    const bf16* __restrict__ VT, const int* __restrict__ pos,
    bf16* __restrict__ AO) {
  __shared__ bf16 Kt0[64 * 32], Kt1[64 * 32];  // K rows, d 0..31 / 32..63
  __shared__ bf16 Vt0[64 * 32], Vt1[64 * 32];  // VT rows (d), c 0..31 / 32..63
  __shared__ bf16 Pbuf[8][16 * PST];

  int bh = blockIdx.x;                 // 0..31
  int qi = 15 - (int)blockIdx.y;       // q-tile of 128, heavy first
  int bb = bh >> 4, h = bh & 15;
  int tid = threadIdx.x;
  int wave = tid >> 6, lane = tid & 63;
  int l15 = lane & 15, quad = lane >> 4;

  int q0 = qi * 128 + wave * 16;       // wave's q base within sequence
  size_t grow = (size_t)bb * T_SZ + q0;

  // ---- load Q fragments and apply RoPE in-register (pairs are in-lane) ----
  const bf16* Qp = Q + (grow + l15) * D_MODEL + h * DH + quad * 8;
  bf16x8 bq0 = *(const bf16x8*)(Qp);
  bf16x8 bq1 = *(const bf16x8*)(Qp + 32);
  {
    float p = (float)pos[q0 + l15];
#pragma unroll
    for (int jj = 0; jj < 4; ++jj) {
      int i0 = quad * 4 + jj;          // d = quad*8 + 2jj   -> i = i0
      float s, c;
      sincosf(p * __expf(-(float)i0 * 0.28782313662425f), &s, &c);
      float x1 = (float)bq0[2 * jj], x2 = (float)bq0[2 * jj + 1];
      bq0[2 * jj]     = (bf16)(x1 * c - x2 * s);
      bq0[2 * jj + 1] = (bf16)(x1 * s + x2 * c);
      sincosf(p * __expf(-(float)(i0 + 16) * 0.28782313662425f), &s, &c);
      float y1 = (float)bq1[2 * jj], y2 = (float)bq1[2 * jj + 1];
      bq1[2 * jj]     = (bf16)(y1 * c - y2 * s);
      bq1[2 * jj + 1] = (bf16)(y1 * s + y2 * c);
    }
  }

  f32x4 o[4];
#pragma unroll
  for (int nt = 0; nt < 4; ++nt) o[nt] = (f32x4){0.f, 0.f, 0.f, 0.f};
  float l_i = 0.f;

  // ---- staging assignment: waves 0-3 -> K halves, waves 4-7 -> VT halves ----
  bool isK = (tid < 256);
  int stid = isK ? tid : tid - 256;
  int srow = stid >> 2, sch = stid & 3;
  const bf16* sbase = isK
      ? K + ((size_t)bb * T_SZ + srow) * D_MODEL + h * DH + sch * 8
      : VT + ((size_t)bh * DH + srow) * T_SZ + sch * 8;
  size_t sstep = isK ? (size_t)64 * D_MODEL : (size_t)64;
  bf16* sdst0 = isK ? &Kt0[srow * 32 + sch * 8] : &Vt0[srow * 32 + sch * 8];
  bf16* sdst1 = isK ? &Kt1[srow * 32 + sch * 8] : &Vt1[srow * 32 + sch * 8];

  bf16* Pw = Pbuf[wave];
  int nchunks = 2 * qi + 2;
  int tb = 2 * qi + (wave >> 2);       // this wave's boundary chunk
  int bound = (wave & 3) * 16 + l15;   // causal boundary within chunk tb

  for (int t = 0; t < nchunks; ++t) {
    const bf16* s = sbase + (size_t)t * sstep;
    async_copy16(s, sdst0);
    async_copy16(s + 32, sdst1);
    __syncthreads();

    if (t <= tb) {
      // ---- S^T = K · Q^T ----
      f32x4 st[4];
#pragma unroll
      for (int cs = 0; cs < 4; ++cs) {
        bf16x8 ak0 = *(const bf16x8*)&Kt0[(cs * 16 + l15) * 32 + quad * 8];
        bf16x8 ak1 = *(const bf16x8*)&Kt1[(cs * 16 + l15) * 32 + quad * 8];
        f32x4 s4 = (f32x4){0.f, 0.f, 0.f, 0.f};
        s4 = __builtin_amdgcn_mfma_f32_16x16x32_bf16(ak0, bq0, s4, 0, 0, 0);
        s4 = __builtin_amdgcn_mfma_f32_16x16x32_bf16(ak1, bq1, s4, 0, 0, 0);
        st[cs] = s4;
      }

      // ---- p = exp(s*scale); mask above diagonal on boundary chunk ----
      bool bm = (t == tb);
      float ps = 0.f;
#pragma unroll
      for (int cs = 0; cs < 4; ++cs)
#pragma unroll
        for (int r = 0; r < 4; ++r) {
          float p = __expf(st[cs][r] * 0.125f);
          if (bm) {
            int cl = cs * 16 + quad * 4 + r;
            p = (cl > bound) ? 0.f : p;
          }
          st[cs][r] = p;
          ps += p;
        }
      l_i += ps;

      // ---- P[q][c] -> per-wave LDS, transpose to B-operand layout ----
#pragma unroll
      for (int cs = 0; cs < 4; ++cs) {
        bf16x4 pk;
#pragma unroll
        for (int r = 0; r < 4; ++r) pk[r] = (bf16)st[cs][r];
        *(bf16x4*)&Pw[l15 * PST + cs * 16 + quad * 4] = pk;
      }
      __asm__ __volatile__("" ::: "memory");
      bf16x8 bp0 = *(const bf16x8*)&Pw[l15 * PST + quad * 8];
      bf16x8 bp1 = *(const bf16x8*)&Pw[l15 * PST + 32 + quad * 8];
      __asm__ __volatile__("" ::: "memory");

      // ---- O^T += V^T · P^T ----
#pragma unroll
      for (int nt = 0; nt < 4; ++nt) {
        bf16x8 av0 = *(const bf16x8*)&Vt0[(nt * 16 + l15) * 32 + quad * 8];
        bf16x8 av1 = *(const bf16x8*)&Vt1[(nt * 16 + l15) * 32 + quad * 8];
        o[nt] = __builtin_amdgcn_mfma_f32_16x16x32_bf16(av0, bp0, o[nt], 0, 0, 0);
        o[nt] = __builtin_amdgcn_mfma_f32_16x16x32_bf16(av1, bp1, o[nt], 0, 0, 0);
      }
    }
    __syncthreads();
  }

  // ---- l reduction across quads, normalize, store ----
  l_i += __shfl_xor(l_i, 16);
  l_i += __shfl_xor(l_i, 32);
  float inv = 1.0f / l_i;
#pragma unroll
  for (int nt = 0; nt < 4; ++nt) {
    bf16x4 ov;
#pragma unroll
    for (int r = 0; r < 4; ++r) ov[r] = (bf16)(o[nt][r] * inv);
    *(bf16x4*)&AO[(grow + l15) * D_MODEL + h * DH + nt * 16 + quad * 4] = ov;
  }
}

// ---------------------------------------------------------------------------
// 5. Output GEMM, m97 structure (unchanged)
// ---------------------------------------------------------------------------
__global__ __launch_bounds__(256) void out_gemm(
    const bf16* __restrict__ AO, const bf16* __restrict__ Wob,
    float* __restrict__ out) {
  __shared__ bf16 As[128 * 32];
  __shared__ bf16 Bs[128 * 32];

  int tid = threadIdx.x;
  int wave = tid >> 6, lane = tid & 63;
  int wm = wave >> 1, wn = wave & 1;
  int l15 = lane & 15, quad = lane >> 4;

  int row0 = blockIdx.x * 128;
  int nb = blockIdx.y * 128;

  int srow = tid >> 2;
  int schunk = tid & 3;
  const bf16* Ag = AO + (size_t)(row0 + srow) * D_MODEL + schunk * 8;
  const bf16* Bg = Wob + (size_t)(nb + srow) * D_MODEL + schunk * 8;
  bf16* Al0 = &As[srow * 32 + schunk * 8];
  bf16* Al1 = &As[(srow + 64) * 32 + schunk * 8];
  bf16* Bl0 = &Bs[srow * 32 + schunk * 8];
  bf16* Bl1 = &Bs[(srow + 64) * 32 + schunk * 8];

  f32x4 acc[4][4];
#pragma unroll
  for (int i = 0; i < 4; ++i)
#pragma unroll
    for (int j = 0; j < 4; ++j) acc[i][j] = (f32x4){0.f, 0.f, 0.f, 0.f};

  for (int k0 = 0; k0 < D_MODEL; k0 += 32) {
    async_copy16(Ag + k0, Al0);
    async_copy16(Ag + k0 + (size_t)64 * D_MODEL, Al1);
    async_copy16(Bg + k0, Bl0);
    async_copy16(Bg + k0 + (size_t)64 * D_MODEL, Bl1);
    __syncthreads();

    bf16x8 af[4], bfr[4];
#pragma unroll
    for (int i = 0; i < 4; ++i)
      af[i] = *(const bf16x8*)&As[(wm * 64 + i * 16 + l15) * 32 + quad * 8];
#pragma unroll
    for (int j = 0; j < 4; ++j)
      bfr[j] = *(const bf16x8*)&Bs[(wn * 64 + j * 16 + l15) * 32 + quad * 8];
#pragma unroll
    for (int i = 0; i < 4; ++i)
#pragma unroll
      for (int j = 0; j < 4; ++j)
        acc[i][j] = __builtin_amdgcn_mfma_f32_16x16x32_bf16(af[i], bfr[j],
                                                            acc[i][j], 0, 0, 0);
    __syncthreads();
  }

#pragma unroll
  for (int i = 0; i < 4; ++i) {
    int row = row0 + wm * 64 + i * 16 + quad * 4;
#pragma unroll
    for (int j = 0; j < 4; ++j) {
      int col = nb + wn * 64 + j * 16 + l15;
#pragma unroll
      for (int r = 0; r < 4; ++r)
        out[(size_t)(row + r) * D_MODEL + col] = acc[i][j][r];
    }
  }
}

// ---------------------------------------------------------------------------
extern "C" void kernel_launch(void* const* d_in, const int* in_sizes, int n_in,
                              void* d_out, int out_size, void* d_ws, size_t ws_size,
                              hipStream_t stream) {
  const float* X  = (const float*)d_in[0];
  const float* Wq = (const float*)d_in[1];
  const float* Wk = (const float*)d_in[2];
  const float* Wv = (const float*)d_in[3];
  const float* Wo = (const float*)d_in[4];
  const int*  pos = (const int*)d_in[5];
  float* out = (float*)d_out;

  char* w = (char*)d_ws;
  bf16* Xb  = (bf16*)w;  w += (size_t)M_ROWS * D_MODEL * 2;
  bf16* Wqb = (bf16*)w;  w += (size_t)D_MODEL * D_MODEL * 2;
  bf16* Wkb = (bf16*)w;  w += (size_t)D_MODEL * D_MODEL * 2;
  bf16* Wvb = (bf16*)w;  w += (size_t)D_MODEL * D_MODEL * 2;
  bf16* Wob = (bf16*)w;  w += (size_t)D_MODEL * D_MODEL * 2;
  bf16* Qb  = (bf16*)w;  w += (size_t)M_ROWS * D_MODEL * 2;
  bf16* Kb  = (bf16*)w;  w += (size_t)M_ROWS * D_MODEL * 2;
  bf16* Vb  = (bf16*)w;  w += (size_t)M_ROWS * D_MODEL * 2;
  bf16* AO  = (bf16*)w;  w += (size_t)M_ROWS * D_MODEL * 2;
  bf16* VT  = (bf16*)w;  w += (size_t)M_ROWS * D_MODEL * 2;

  cast_all<<<(NX + 4 * NW) / 256, 256, 0, stream>>>(X, Wq, Wk, Wv, Wo,
                                                    Xb, Wqb, Wkb, Wvb, Wob);
  qkv_gemm<<<dim3(M_ROWS / 128, 3 * D_MODEL / 128), 256, 0, stream>>>(
      Xb, Wqb, Wkb, Wvb, Qb, Kb, Vb);
  ropek_vt<<<ROPEK_BLOCKS + B_SZ * NUM_HEADS * (T_SZ / 64), 256, 0, stream>>>(
      Kb, Vb, VT, pos);
  attn_kernel<<<dim3(B_SZ * NUM_HEADS, T_SZ / 128), 512, 0, stream>>>(
      Qb, Kb, VT, pos, AO);
  out_gemm<<<dim3(M_ROWS / 128, D_MODEL / 128), 256, 0, stream>>>(AO, Wob, out);
}

// Round 8
// 185.560 us; speedup vs baseline: 1.0568x; 1.0568x over previous
//
#include <hip/hip_runtime.h>

#define D_MODEL 1024
#define NUM_HEADS 16
#define DH 64
#define B_SZ 2
#define T_SZ 2048
#define M_ROWS (B_SZ * T_SZ)   // 4096

typedef __bf16 bf16;
typedef __bf16 bf16x4 __attribute__((ext_vector_type(4)));
typedef __bf16 bf16x8 __attribute__((ext_vector_type(8)));
typedef float f32x4 __attribute__((ext_vector_type(4)));

__device__ __forceinline__ void async_copy16(const bf16* g, bf16* l) {
  __builtin_amdgcn_global_load_lds(
      (const __attribute__((address_space(1))) void*)g,
      (__attribute__((address_space(3))) void*)l, 16, 0, 0);
}

// ---------------------------------------------------------------------------
// 1. Cast fp32 -> bf16
// ---------------------------------------------------------------------------
#define NX (M_ROWS * D_MODEL / 4)
#define NW (D_MODEL * D_MODEL / 4)

__global__ __launch_bounds__(256) void cast_all(
    const float* __restrict__ X, const float* __restrict__ Wq,
    const float* __restrict__ Wk, const float* __restrict__ Wv,
    const float* __restrict__ Wo,
    bf16* __restrict__ Xb, bf16* __restrict__ Wqb, bf16* __restrict__ Wkb,
    bf16* __restrict__ Wvb, bf16* __restrict__ Wob) {
  int i = blockIdx.x * 256 + threadIdx.x;
  const float* s; bf16* d; int off;
  if (i < NX) {
    s = X; d = Xb; off = i;
  } else {
    int j = i - NX;
    int w = j >> 18;
    off = j & (NW - 1);
    if (w == 0)      { s = Wq; d = Wqb; }
    else if (w == 1) { s = Wk; d = Wkb; }
    else if (w == 2) { s = Wv; d = Wvb; }
    else             { s = Wo; d = Wob; }
  }
  float4 v = ((const float4*)s)[off];
  bf16x4 o;
  o[0] = (bf16)v.x; o[1] = (bf16)v.y; o[2] = (bf16)v.z; o[3] = (bf16)v.w;
  ((bf16x4*)d)[off] = o;
}

// ---------------------------------------------------------------------------
// 2. QKV GEMM, m97 structure (unchanged)
// ---------------------------------------------------------------------------
__global__ __launch_bounds__(256) void qkv_gemm(
    const bf16* __restrict__ Xb,
    const bf16* __restrict__ Wqb, const bf16* __restrict__ Wkb,
    const bf16* __restrict__ Wvb,
    bf16* __restrict__ Q, bf16* __restrict__ K, bf16* __restrict__ V) {
  __shared__ bf16 As[128 * 32];
  __shared__ bf16 Bs[128 * 32];

  int tid = threadIdx.x;
  int wave = tid >> 6, lane = tid & 63;
  int wm = wave >> 1, wn = wave & 1;
  int l15 = lane & 15, quad = lane >> 4;

  int row0 = blockIdx.x * 128;
  int col0 = blockIdx.y * 128;
  int sel = col0 >> 10;
  int nb = col0 & 1023;
  const bf16* W; bf16* Out;
  if (sel == 0)      { W = Wqb; Out = Q; }
  else if (sel == 1) { W = Wkb; Out = K; }
  else               { W = Wvb; Out = V; }

  int srow = tid >> 2;
  int schunk = tid & 3;
  const bf16* Ag = Xb + (size_t)(row0 + srow) * D_MODEL + schunk * 8;
  const bf16* Bg = W + (size_t)(nb + srow) * D_MODEL + schunk * 8;
  bf16* Al0 = &As[srow * 32 + schunk * 8];
  bf16* Al1 = &As[(srow + 64) * 32 + schunk * 8];
  bf16* Bl0 = &Bs[srow * 32 + schunk * 8];
  bf16* Bl1 = &Bs[(srow + 64) * 32 + schunk * 8];

  f32x4 acc[4][4];
#pragma unroll
  for (int i = 0; i < 4; ++i)
#pragma unroll
    for (int j = 0; j < 4; ++j) acc[i][j] = (f32x4){0.f, 0.f, 0.f, 0.f};

  for (int k0 = 0; k0 < D_MODEL; k0 += 32) {
    async_copy16(Ag + k0, Al0);
    async_copy16(Ag + k0 + (size_t)64 * D_MODEL, Al1);
    async_copy16(Bg + k0, Bl0);
    async_copy16(Bg + k0 + (size_t)64 * D_MODEL, Bl1);
    __syncthreads();

    bf16x8 af[4], bfr[4];
#pragma unroll
    for (int i = 0; i < 4; ++i)
      af[i] = *(const bf16x8*)&As[(wm * 64 + i * 16 + l15) * 32 + quad * 8];
#pragma unroll
    for (int j = 0; j < 4; ++j)
      bfr[j] = *(const bf16x8*)&Bs[(wn * 64 + j * 16 + l15) * 32 + quad * 8];
#pragma unroll
    for (int i = 0; i < 4; ++i)
#pragma unroll
      for (int j = 0; j < 4; ++j)
        acc[i][j] = __builtin_amdgcn_mfma_f32_16x16x32_bf16(af[i], bfr[j],
                                                            acc[i][j], 0, 0, 0);
    __syncthreads();
  }

#pragma unroll
  for (int i = 0; i < 4; ++i) {
    int row = row0 + wm * 64 + i * 16 + quad * 4;
#pragma unroll
    for (int j = 0; j < 4; ++j) {
      int col = nb + wn * 64 + j * 16 + l15;
#pragma unroll
      for (int r = 0; r < 4; ++r)
        Out[(size_t)(row + r) * D_MODEL + col] = (bf16)acc[i][j][r];
    }
  }
}

// ---------------------------------------------------------------------------
// 3. Fused: RoPE on K (in place) + V transpose (K-only; Q roped in attn)
// ---------------------------------------------------------------------------
#define ROPEK_BLOCKS (M_ROWS * NUM_HEADS * 32 / 256)   // 8192

__global__ __launch_bounds__(256) void ropek_vt(
    bf16* __restrict__ K, const bf16* __restrict__ V, bf16* __restrict__ VT,
    const int* __restrict__ pos) {
  int b0 = blockIdx.x;
  if (b0 < ROPEK_BLOCKS) {
    int idx = b0 * 256 + threadIdx.x;
    int i = idx & 31;
    int h = (idx >> 5) & 15;
    int row = idx >> 9;
    int t = row & (T_SZ - 1);
    float p = (float)pos[t];
    float freq = __expf(-(float)i * 0.28782313662425f);  // ln(1e4)/32
    float s, c;
    sincosf(p * freq, &s, &c);
    size_t base = (size_t)row * D_MODEL + h * DH + 2 * i;
    float k1 = (float)K[base], k2 = (float)K[base + 1];
    K[base]     = (bf16)(k1 * c - k2 * s);
    K[base + 1] = (bf16)(k1 * s + k2 * c);
  } else {
    __shared__ bf16 tile[64][72];
    int vb = b0 - ROPEK_BLOCKS;
    int bh = vb >> 5;
    int tt = vb & 31;
    int b = bh >> 4, h = bh & 15;
    int tid = threadIdx.x;
    int rr = tid >> 3;
    int cc = (tid & 7) * 8;
#pragma unroll
    for (int p = 0; p < 2; ++p) {
      int t = rr + p * 32;
      bf16x8 v = *(const bf16x8*)&V[((size_t)b * T_SZ + tt * 64 + t) * D_MODEL +
                                    h * DH + cc];
      *(bf16x8*)&tile[t][cc] = v;
    }
    __syncthreads();
#pragma unroll
    for (int p = 0; p < 2; ++p) {
      int d = rr + p * 32;
      bf16x8 o;
#pragma unroll
      for (int j = 0; j < 8; ++j) o[j] = tile[cc + j][d];
      *(bf16x8*)&VT[((size_t)bh * DH + d) * T_SZ + tt * 64 + cc] = o;
    }
  }
}

// ---------------------------------------------------------------------------
// 4. Causal flash attention, R5 structure + conflict-free padded LDS staging.
//    Block = 4 waves, q-tile 64 (wave owns 16 rows). kv chunks of 64 staged
//    manually (global->VGPR->ds_write_b128) into 72-elem-stride tiles so the
//    A-frag ds_read_b128s are 2-way (free) instead of ~8-way conflicted.
//    One-chunk register prefetch hides global latency. Q-RoPE in-register.
// ---------------------------------------------------------------------------
#define PST 72
#define KST 72

__global__ __launch_bounds__(256) void attn_kernel(
    const bf16* __restrict__ Q, const bf16* __restrict__ K,
    const bf16* __restrict__ VT, const int* __restrict__ pos,
    bf16* __restrict__ AO) {
  __shared__ bf16 Kt[64 * KST];          // K rows (kv), d 0..63, stride 72
  __shared__ bf16 Vt[64 * KST];          // VT rows (d), c 0..63, stride 72
  __shared__ bf16 Pbuf[4][16 * PST];

  int bh = blockIdx.x;                   // 0..31
  int qi = 31 - (int)blockIdx.y;         // q-tile of 64, heavy first
  int bb = bh >> 4, h = bh & 15;
  int tid = threadIdx.x;
  int wave = tid >> 6, lane = tid & 63;
  int l15 = lane & 15, quad = lane >> 4;

  int q0 = qi * 64 + wave * 16;
  size_t grow = (size_t)bb * T_SZ + q0;

  // ---- Q fragments + in-register RoPE (pairs are in-lane) ----
  const bf16* Qp = Q + (grow + l15) * D_MODEL + h * DH + quad * 8;
  bf16x8 bq0 = *(const bf16x8*)(Qp);
  bf16x8 bq1 = *(const bf16x8*)(Qp + 32);
  {
    float p = (float)pos[q0 + l15];
#pragma unroll
    for (int jj = 0; jj < 4; ++jj) {
      int i0 = quad * 4 + jj;
      float s, c;
      sincosf(p * __expf(-(float)i0 * 0.28782313662425f), &s, &c);
      float x1 = (float)bq0[2 * jj], x2 = (float)bq0[2 * jj + 1];
      bq0[2 * jj]     = (bf16)(x1 * c - x2 * s);
      bq0[2 * jj + 1] = (bf16)(x1 * s + x2 * c);
      sincosf(p * __expf(-(float)(i0 + 16) * 0.28782313662425f), &s, &c);
      float y1 = (float)bq1[2 * jj], y2 = (float)bq1[2 * jj + 1];
      bq1[2 * jj]     = (bf16)(y1 * c - y2 * s);
      bq1[2 * jj + 1] = (bf16)(y1 * s + y2 * c);
    }
  }

  f32x4 o[4];
#pragma unroll
  for (int nt = 0; nt < 4; ++nt) o[nt] = (f32x4){0.f, 0.f, 0.f, 0.f};
  float l_i = 0.f;

  // ---- staging: thread covers K row tid>>2 (16 d-elems) + same for VT ----
  int srow = tid >> 2;                   // 0..63
  int sc = (tid & 3) * 16;               // elem col base (32 B per thread)
  const bf16* Kg = K + ((size_t)bb * T_SZ + srow) * D_MODEL + h * DH + sc;
  const bf16* Vg = VT + ((size_t)bh * DH + srow) * T_SZ + sc;
  bf16* Kl = &Kt[srow * KST + sc];
  bf16* Vl = &Vt[srow * KST + sc];

  bf16* Pw = Pbuf[wave];
  int nchunks = qi + 1;
  int rel = wave * 16 + l15;             // causal boundary (last chunk)

  // prefetch chunk 0
  bf16x8 kr0 = *(const bf16x8*)(Kg);
  bf16x8 kr1 = *(const bf16x8*)(Kg + 8);
  bf16x8 vr0 = *(const bf16x8*)(Vg);
  bf16x8 vr1 = *(const bf16x8*)(Vg + 8);

  for (int t = 0; t < nchunks; ++t) {
    __syncthreads();                     // previous compute done; LDS writable
    *(bf16x8*)(Kl) = kr0;
    *(bf16x8*)(Kl + 8) = kr1;
    *(bf16x8*)(Vl) = vr0;
    *(bf16x8*)(Vl + 8) = vr1;
    if (t + 1 < nchunks) {               // prefetch next chunk into registers
      const bf16* Kn = Kg + (size_t)(t + 1) * 64 * D_MODEL;
      const bf16* Vn = Vg + (t + 1) * 64;
      kr0 = *(const bf16x8*)(Kn);
      kr1 = *(const bf16x8*)(Kn + 8);
      vr0 = *(const bf16x8*)(Vn);
      vr1 = *(const bf16x8*)(Vn + 8);
    }
    __syncthreads();                     // tiles ready

    // ---- S^T = K · Q^T ----
    f32x4 st[4];
#pragma unroll
    for (int cs = 0; cs < 4; ++cs) {
      bf16x8 ak0 = *(const bf16x8*)&Kt[(cs * 16 + l15) * KST + quad * 8];
      bf16x8 ak1 = *(const bf16x8*)&Kt[(cs * 16 + l15) * KST + 32 + quad * 8];
      f32x4 s4 = (f32x4){0.f, 0.f, 0.f, 0.f};
      s4 = __builtin_amdgcn_mfma_f32_16x16x32_bf16(ak0, bq0, s4, 0, 0, 0);
      s4 = __builtin_amdgcn_mfma_f32_16x16x32_bf16(ak1, bq1, s4, 0, 0, 0);
      st[cs] = s4;
    }

    // ---- p = exp(s*scale); mask above diagonal on last chunk ----
    bool last = (t == nchunks - 1);
    float ps = 0.f;
#pragma unroll
    for (int cs = 0; cs < 4; ++cs)
#pragma unroll
      for (int r = 0; r < 4; ++r) {
        float p = __expf(st[cs][r] * 0.125f);
        if (last) {
          int cl = cs * 16 + quad * 4 + r;
          p = (cl > rel) ? 0.f : p;
        }
        st[cs][r] = p;
        ps += p;
      }
    l_i += ps;

    // ---- P[q][c] -> per-wave LDS, transpose to B-operand layout ----
#pragma unroll
    for (int cs = 0; cs < 4; ++cs) {
      bf16x4 pk;
#pragma unroll
      for (int r = 0; r < 4; ++r) pk[r] = (bf16)st[cs][r];
      *(bf16x4*)&Pw[l15 * PST + cs * 16 + quad * 4] = pk;
    }
    __asm__ __volatile__("" ::: "memory");
    bf16x8 bp0 = *(const bf16x8*)&Pw[l15 * PST + quad * 8];
    bf16x8 bp1 = *(const bf16x8*)&Pw[l15 * PST + 32 + quad * 8];
    __asm__ __volatile__("" ::: "memory");

    // ---- O^T += V^T · P^T ----
#pragma unroll
    for (int nt = 0; nt < 4; ++nt) {
      bf16x8 av0 = *(const bf16x8*)&Vt[(nt * 16 + l15) * KST + quad * 8];
      bf16x8 av1 = *(const bf16x8*)&Vt[(nt * 16 + l15) * KST + 32 + quad * 8];
      o[nt] = __builtin_amdgcn_mfma_f32_16x16x32_bf16(av0, bp0, o[nt], 0, 0, 0);
      o[nt] = __builtin_amdgcn_mfma_f32_16x16x32_bf16(av1, bp1, o[nt], 0, 0, 0);
    }
  }

  // ---- l reduction across quads, normalize, store ----
  l_i += __shfl_xor(l_i, 16);
  l_i += __shfl_xor(l_i, 32);
  float inv = 1.0f / l_i;
#pragma unroll
  for (int nt = 0; nt < 4; ++nt) {
    bf16x4 ov;
#pragma unroll
    for (int r = 0; r < 4; ++r) ov[r] = (bf16)(o[nt][r] * inv);
    *(bf16x4*)&AO[(grow + l15) * D_MODEL + h * DH + nt * 16 + quad * 4] = ov;
  }
}

// ---------------------------------------------------------------------------
// 5. Output GEMM: 128x64 tiles -> 512 blocks (2/CU instead of 1/CU)
// ---------------------------------------------------------------------------
__global__ __launch_bounds__(256) void out_gemm(
    const bf16* __restrict__ AO, const bf16* __restrict__ Wob,
    float* __restrict__ out) {
  __shared__ bf16 As[128 * 32];
  __shared__ bf16 Bs[64 * 32];

  int tid = threadIdx.x;
  int wave = tid >> 6, lane = tid & 63;
  int l15 = lane & 15, quad = lane >> 4;

  int row0 = blockIdx.x * 128;
  int nb = blockIdx.y * 64;

  int srow = tid >> 2;
  int schunk = tid & 3;
  const bf16* Ag = AO + (size_t)(row0 + srow) * D_MODEL + schunk * 8;
  const bf16* Bg = Wob + (size_t)(nb + srow) * D_MODEL + schunk * 8;
  bf16* Al0 = &As[srow * 32 + schunk * 8];
  bf16* Al1 = &As[(srow + 64) * 32 + schunk * 8];
  bf16* Bl = &Bs[srow * 32 + schunk * 8];

  f32x4 acc[2][4];
#pragma unroll
  for (int i = 0; i < 2; ++i)
#pragma unroll
    for (int j = 0; j < 4; ++j) acc[i][j] = (f32x4){0.f, 0.f, 0.f, 0.f};

  for (int k0 = 0; k0 < D_MODEL; k0 += 32) {
    async_copy16(Ag + k0, Al0);
    async_copy16(Ag + k0 + (size_t)64 * D_MODEL, Al1);
    async_copy16(Bg + k0, Bl);
    __syncthreads();

    bf16x8 af[2], bfr[4];
#pragma unroll
    for (int i = 0; i < 2; ++i)
      af[i] = *(const bf16x8*)&As[(wave * 32 + i * 16 + l15) * 32 + quad * 8];
#pragma unroll
    for (int j = 0; j < 4; ++j)
      bfr[j] = *(const bf16x8*)&Bs[(j * 16 + l15) * 32 + quad * 8];
#pragma unroll
    for (int i = 0; i < 2; ++i)
#pragma unroll
      for (int j = 0; j < 4; ++j)
        acc[i][j] = __builtin_amdgcn_mfma_f32_16x16x32_bf16(af[i], bfr[j],
                                                            acc[i][j], 0, 0, 0);
    __syncthreads();
  }

#pragma unroll
  for (int i = 0; i < 2; ++i) {
    int row = row0 + wave * 32 + i * 16 + quad * 4;
#pragma unroll
    for (int j = 0; j < 4; ++j) {
      int col = nb + j * 16 + l15;
#pragma unroll
      for (int r = 0; r < 4; ++r)
        out[(size_t)(row + r) * D_MODEL + col] = acc[i][j][r];
    }
  }
}

// ---------------------------------------------------------------------------
extern "C" void kernel_launch(void* const* d_in, const int* in_sizes, int n_in,
                              void* d_out, int out_size, void* d_ws, size_t ws_size,
                              hipStream_t stream) {
  const float* X  = (const float*)d_in[0];
  const float* Wq = (const float*)d_in[1];
  const float* Wk = (const float*)d_in[2];
  const float* Wv = (const float*)d_in[3];
  const float* Wo = (const float*)d_in[4];
  const int*  pos = (const int*)d_in[5];
  float* out = (float*)d_out;

  char* w = (char*)d_ws;
  bf16* Xb  = (bf16*)w;  w += (size_t)M_ROWS * D_MODEL * 2;
  bf16* Wqb = (bf16*)w;  w += (size_t)D_MODEL * D_MODEL * 2;
  bf16* Wkb = (bf16*)w;  w += (size_t)D_MODEL * D_MODEL * 2;
  bf16* Wvb = (bf16*)w;  w += (size_t)D_MODEL * D_MODEL * 2;
  bf16* Wob = (bf16*)w;  w += (size_t)D_MODEL * D_MODEL * 2;
  bf16* Qb  = (bf16*)w;  w += (size_t)M_ROWS * D_MODEL * 2;
  bf16* Kb  = (bf16*)w;  w += (size_t)M_ROWS * D_MODEL * 2;
  bf16* Vb  = (bf16*)w;  w += (size_t)M_ROWS * D_MODEL * 2;
  bf16* AO  = (bf16*)w;  w += (size_t)M_ROWS * D_MODEL * 2;
  bf16* VT  = (bf16*)w;  w += (size_t)M_ROWS * D_MODEL * 2;

  cast_all<<<(NX + 4 * NW) / 256, 256, 0, stream>>>(X, Wq, Wk, Wv, Wo,
                                                    Xb, Wqb, Wkb, Wvb, Wob);
  qkv_gemm<<<dim3(M_ROWS / 128, 3 * D_MODEL / 128), 256, 0, stream>>>(
      Xb, Wqb, Wkb, Wvb, Qb, Kb, Vb);
  ropek_vt<<<ROPEK_BLOCKS + B_SZ * NUM_HEADS * (T_SZ / 64), 256, 0, stream>>>(
      Kb, Vb, VT, pos);
  attn_kernel<<<dim3(B_SZ * NUM_HEADS, T_SZ / 64), 256, 0, stream>>>(
      Qb, Kb, VT, pos, AO);
  out_gemm<<<dim3(M_ROWS / 128, D_MODEL / 64), 256, 0, stream>>>(AO, Wob, out);
}